// Round 5
// baseline (167.111 us; speedup 1.0000x reference)
//
#include <hip/hip_runtime.h>
#include <hip/hip_bf16.h>
#include <stdint.h>

// Problem constants (from reference)
#define B_   32
#define C_   3
#define H_   384
#define W_   384
#define HW_  (H_ * W_)      // 147456
#define N_   576
#define ED   768            // embed dim (output features)
#define KF   768            // in features = 3*16*16
#define M_   (B_ * N_)      // 18432 patch rows

typedef __attribute__((ext_vector_type(8))) short   short8;
typedef __attribute__((ext_vector_type(8))) unsigned short ushort8;
typedef __attribute__((ext_vector_type(4))) float   f32x4;
typedef __attribute__((ext_vector_type(4))) unsigned int uint4v;

// fp32 -> bf16 with round-to-nearest-even (used for W only)
__device__ __forceinline__ unsigned short f2bf(float f) {
    union { float f; unsigned int u; } v; v.f = f;
    unsigned int u = v.u;
    return (unsigned short)((u + 0x7FFFu + ((u >> 16) & 1u)) >> 16);
}

// ---------------------------------------------------------------------------
// Kernel 1: proj_w fp32 -> bf16 [ED][KF] row-major (B^T layout, K contiguous)
// ---------------------------------------------------------------------------
__global__ __launch_bounds__(256) void conv_w(
    const float* __restrict__ w, unsigned short* __restrict__ Wb) {
    int gid = blockIdx.x * 256 + threadIdx.x;          // ED*KF/8 threads
    const float4* s = (const float4*)w + (size_t)gid * 2;
    float4 a = s[0], bq = s[1];
    ushort8 o;
    o[0] = f2bf(a.x);  o[1] = f2bf(a.y);  o[2] = f2bf(a.z);  o[3] = f2bf(a.w);
    o[4] = f2bf(bq.x); o[5] = f2bf(bq.y); o[6] = f2bf(bq.z); o[7] = f2bf(bq.w);
    *(ushort8*)(Wb + (size_t)gid * 8) = o;
}

// ---------------------------------------------------------------------------
// Kernel 2: FUSED gather + bf16 GEMM. out[m][e] = sum_k A[m][k]*W[e][k] + b[e]
// A is gathered per K-iter directly from x (fp32, 4B-aligned rows) into
// XOR-swizzled LDS (write-side swizzle: slot' = slot ^ (m_loc&7), matching
// the fragment-read XOR). B staged via global_load_lds with source-side
// swizzle (unchanged from round 4, which measured 0 bank conflicts).
// Sync structure identical to round 4 (2 barriers / K-iter).
// k = c*256 + ph*16 + pw; K-iter kt: c = kt>>2, ph in [4*(kt&3), +4).
// Thread t gathers rows (m_loc = t&127) x {p0 = t>>7, p0+2} of the 4-ph band:
// 16 floats each (64B, 4B-aligned), round-half-up pack via v_perm_b32,
// two ds_write_b128 per row into swizzled slots (uniform 8-touch/bank =
// conflict-free b128 floor). m / h_idx / w_idx are loop-invariant per thread.
// ---------------------------------------------------------------------------
#define GLD16(g, l)                                                        \
    __builtin_amdgcn_global_load_lds(                                      \
        (const __attribute__((address_space(1))) unsigned int*)(g),        \
        (__attribute__((address_space(3))) unsigned int*)(l), 16, 0, 0)

#define BK 64

__device__ __forceinline__ unsigned int pkbf(unsigned int hi, unsigned int lo) {
    // word = bf16(lo) | bf16(hi)<<16, both rounded half-up (bits pre-biased)
    return __builtin_amdgcn_perm(hi, lo, 0x07060302);
}

__global__ __launch_bounds__(256) void gemm_fused(
    const float* __restrict__ x, const int* __restrict__ h_idx,
    const int* __restrict__ w_idx, const unsigned short* __restrict__ Wb,
    const float* __restrict__ bias, float* __restrict__ out) {
    __shared__ unsigned short sA[128 * BK];   // 16 KiB
    __shared__ unsigned short sB[128 * BK];   // 16 KiB

    const int t = threadIdx.x;

    // XCD-aware bijective block swizzle (864 % 8 == 0)
    const int lin = blockIdx.y * 6 + blockIdx.x;
    const int swz = (lin & 7) * 108 + (lin >> 3);
    const int m0  = (swz / 6) * 128;
    const int e0  = (swz % 6) * 128;

    const int lane = t & 63;
    const int wid  = t >> 6;
    const int wr   = wid >> 1;
    const int wc   = wid & 1;
    const int r16  = lane & 15;
    const int kh   = lane >> 4;

    // ---- A-gather per-thread invariants ----
    const int m_loc = t & 127;
    const int p0    = t >> 7;               // 0 or 1; second row uses p0+2
    const int m     = m0 + m_loc;
    const int bb    = m / N_;
    const int h     = h_idx[m];
    const int w     = w_idx[m];
    const float* xb = x + (size_t)(bb * C_) * HW_ + (size_t)h * W_ + w;
    const int m7 = m_loc & 7;
    char* sAb = (char*)sA;
    const int rb  = m_loc * 128;            // row byte base (64 bf16 = 128B)
    const int a00 = rb + (((2 * p0    ) ^ m7) << 4);
    const int a01 = rb + (((2 * p0 + 1) ^ m7) << 4);
    const int a10 = rb + (((2 * p0 + 4) ^ m7) << 4);   // p0+2 -> slots 2p0+4/5
    const int a11 = rb + (((2 * p0 + 5) ^ m7) << 4);

    // ---- B staging source precompute (source-side slot swizzle) ----
    int st_row[4], st_gc[4];
#pragma unroll
    for (int r = 0; r < 4; ++r) {
        const int o   = r * 4096 + t * 16;
        const int row = o >> 7;
        const int s   = (o >> 4) & 7;
        st_row[r] = row;
        st_gc[r]  = (s ^ (row & 7)) * 8;
    }

    f32x4 acc[4][4];
#pragma unroll
    for (int i = 0; i < 4; ++i)
#pragma unroll
        for (int j = 0; j < 4; ++j) acc[i][j] = (f32x4)0.0f;

    for (int kt = 0; kt < KF / BK; ++kt) {
        const int k0  = kt * BK;
        const int c   = kt >> 2;
        const int ph0 = (kt & 3) * 4;

        // B-tile staging (16 KiB, 4 x GLD16 per thread)
#pragma unroll
        for (int r = 0; r < 4; ++r)
            GLD16(Wb + (size_t)(e0 + st_row[r]) * KF + k0 + st_gc[r],
                  (char*)sB + r * 4096 + t * 16);

        // A-tile gather: two 16-float patch rows -> bf16 -> swizzled LDS
        const float* r0p = xb + (size_t)c * HW_ + (size_t)(ph0 + p0) * W_;
        const float* r1p = r0p + 2 * W_;
        {
            float fv[16];
            __builtin_memcpy(fv, r0p, 64);           // 4B-aligned, 64B
            unsigned int u[16];
#pragma unroll
            for (int i = 0; i < 16; ++i) {
                union { float f; unsigned int u; } cv; cv.f = fv[i];
                u[i] = cv.u + 0x8000u;               // round-half-up bias
            }
            uint4v lo = { pkbf(u[1], u[0]), pkbf(u[3], u[2]),
                          pkbf(u[5], u[4]), pkbf(u[7], u[6]) };
            uint4v hi = { pkbf(u[9], u[8]),  pkbf(u[11], u[10]),
                          pkbf(u[13], u[12]), pkbf(u[15], u[14]) };
            *(uint4v*)(sAb + a00) = lo;
            *(uint4v*)(sAb + a01) = hi;
        }
        {
            float fv[16];
            __builtin_memcpy(fv, r1p, 64);
            unsigned int u[16];
#pragma unroll
            for (int i = 0; i < 16; ++i) {
                union { float f; unsigned int u; } cv; cv.f = fv[i];
                u[i] = cv.u + 0x8000u;
            }
            uint4v lo = { pkbf(u[1], u[0]), pkbf(u[3], u[2]),
                          pkbf(u[5], u[4]), pkbf(u[7], u[6]) };
            uint4v hi = { pkbf(u[9], u[8]),  pkbf(u[11], u[10]),
                          pkbf(u[13], u[12]), pkbf(u[15], u[14]) };
            *(uint4v*)(sAb + a10) = lo;
            *(uint4v*)(sAb + a11) = hi;
        }
        __syncthreads();   // drains vmcnt (B GLD16) + lgkm (A ds_writes)

#pragma unroll
        for (int kk = 0; kk < 2; ++kk) {
            short8 af[4], bf[4];
#pragma unroll
            for (int mi = 0; mi < 4; ++mi) {
                const int ar = wr * 64 + mi * 16 + r16;
                const int sl = ((kk << 2) + kh) ^ (ar & 7);
                af[mi] = *(const short8*)&sA[ar * BK + sl * 8];
            }
#pragma unroll
            for (int ni = 0; ni < 4; ++ni) {
                const int br = wc * 64 + ni * 16 + r16;
                const int sl = ((kk << 2) + kh) ^ (br & 7);
                bf[ni] = *(const short8*)&sB[br * BK + sl * 8];
            }
#pragma unroll
            for (int mi = 0; mi < 4; ++mi)
#pragma unroll
                for (int ni = 0; ni < 4; ++ni)
                    acc[mi][ni] = __builtin_amdgcn_mfma_f32_16x16x32_bf16(
                        af[mi], bf[ni], acc[mi][ni], 0, 0, 0);
        }
        __syncthreads();
    }

    // Epilogue: C/D layout col = lane&15, row = (lane>>4)*4 + j  [m89]
#pragma unroll
    for (int mi = 0; mi < 4; ++mi) {
#pragma unroll
        for (int ni = 0; ni < 4; ++ni) {
            const int ge = e0 + wc * 64 + ni * 16 + r16;
            const float bv = bias[ge];
#pragma unroll
            for (int j = 0; j < 4; ++j) {
                const int gm = m0 + wr * 64 + mi * 16 + kh * 4 + j;
                out[(size_t)gm * ED + ge] = acc[mi][ni][j] + bv;
            }
        }
    }
}

// ---------------------------------------------------------------------------
extern "C" void kernel_launch(void* const* d_in, const int* in_sizes, int n_in,
                              void* d_out, int out_size, void* d_ws, size_t ws_size,
                              hipStream_t stream) {
    const float* x      = (const float*)d_in[0];
    const int*   h_idx  = (const int*)  d_in[1];
    const int*   w_idx  = (const int*)  d_in[2];
    const float* proj_w = (const float*)d_in[3];
    const float* proj_b = (const float*)d_in[4];
    float*       out    = (float*)d_out;

    // Workspace: only Wb bf16 [ED][KF] (1.2 MB) now — A is gathered in-GEMM.
    unsigned short* Wws = (unsigned short*)d_ws;

    conv_w<<<(ED * KF / 8) / 256, 256, 0, stream>>>(proj_w, Wws);
    gemm_fused<<<dim3(ED / 128, M_ / 128), 256, 0, stream>>>(
        x, h_idx, w_idx, Wws, proj_b, out);
}